// Round 12
// baseline (77.611 us; speedup 1.0000x reference)
//
#include <hip/hip_runtime.h>
#include <hip/hip_bf16.h>

typedef __attribute__((ext_vector_type(8))) __bf16 bf16x8;
typedef __attribute__((ext_vector_type(4))) float f32x4;

static constexpr int BROWS = 65536;
static constexpr int SDIM  = 512;
static constexpr int CDIM  = 256;
static constexpr float SLOPE = 0.01f;
static constexpr float HLP = 0.9189385332046727f;  // 0.5*log(2*pi)

// ws bf16 layout: W1T [64][512], W2T [32][64], W3T [256][32]
static constexpr int W1T_OFF = 0;
static constexpr int W2T_OFF = 64 * 512;
static constexpr int W3T_OFF = 64 * 512 + 32 * 64;
static constexpr int WS_ELEMS = W3T_OFF + 256 * 32;   // 43008

__global__ __launch_bounds__(256) void prep_weights(
    const float* __restrict__ W1, const float* __restrict__ W2,
    const float* __restrict__ W3, __bf16* __restrict__ ws)
{
    int tid = blockIdx.x * 256 + threadIdx.x;
    if (tid < 64 * 512) {                       // W1 [512][64] -> W1T [64][512]
        int n = tid >> 9, k = tid & 511;
        ws[W1T_OFF + tid] = (__bf16)W1[k * 64 + n];
    } else if (tid < 64 * 512 + 32 * 64) {      // W2 [64][32] -> W2T [32][64]
        int t = tid - 64 * 512;
        int n = t >> 6, k = t & 63;
        ws[W2T_OFF + t] = (__bf16)W2[k * 32 + n];
    } else if (tid < WS_ELEMS) {                // W3 [32][256] -> W3T [256][32]
        int t = tid - (64 * 512 + 32 * 64);
        int n = t >> 5, k = t & 31;
        ws[W3T_OFF + t] = (__bf16)W3[k * 256 + n];
    }
}

// swizzled LDS element index for bf16 [16][64] tiles: row stride 128 B
__device__ __forceinline__ int swz(int row, int elem) {
    return (row * 64 + elem) ^ ((row & 7) << 3);
}

__device__ __forceinline__ bf16x8 cvt8(f32x4 a, f32x4 b) {
    bf16x8 r = {(__bf16)a.x, (__bf16)a.y, (__bf16)a.z, (__bf16)a.w,
                (__bf16)b.x, (__bf16)b.y, (__bf16)b.z, (__bf16)b.w};
    return r;
}

static constexpr int MT_STRIDE = 68;     // floats
static constexpr int WREGION = 8704;     // per-wave: two 4352-B DMA chunk buffers

// R11 structure (counted-vmcnt DMA streaming) + NON-TEMPORAL READS for the two
// single-use streams (state via DMA aux-NT, noise via __builtin_nontemporal_load):
// they are read exactly once per dispatch, so L3 allocation is pure pollution —
// NT keeps L3 for the reused weights and lets the streams ride HBM at full BW.
__global__ __launch_bounds__(256, 4) void policy_fused(
    const float* __restrict__ state, const float* __restrict__ b1,
    const float* __restrict__ b2, const float* __restrict__ b3,
    const float* __restrict__ noise, const __bf16* __restrict__ ws,
    float* __restrict__ actions, float* __restrict__ logp)
{
    __shared__ __align__(64) char ldsraw[4 * WREGION];   // 34816 B

    const int tid  = threadIdx.x;
    const int wave = tid >> 6;
    const int lane = tid & 63;
    const int lr   = lane & 15;   // A-row / B-col index
    const int lq   = lane >> 4;   // k-chunk / C-row-quad index

    const int rowbase = blockIdx.x * 64 + wave * 16;   // this wave's 16 rows

    char* region = ldsraw + wave * WREGION;

    const __bf16* W1T = ws + W1T_OFF;
    const __bf16* W2T = ws + W2T_OFF;
    const __bf16* W3T = ws + W3T_OFF;

    const f32x4 zero4 = {0.f, 0.f, 0.f, 0.f};

    // preload tiny biases (reused across all waves -> cached normally)
    float bv1[4], bv2[2];
    #pragma unroll
    for (int n = 0; n < 4; ++n) bv1[n] = b1[n * 16 + lr];
    #pragma unroll
    for (int n = 0; n < 2; ++n) bv2[n] = b2[n * 16 + lr];

    // ---------------- layer 1: DMA-pipelined, 8 chunks of K=64 ----------------
    const int dma_row = lane >> 4;          // 0..3 within group
    const int dma_s   = lane & 15;          // 16-B slot

// aux=2: NT cache-policy bit on the MUBUF/global DMA (single-use stream; do not
// allocate in L2/L3). If the bit is ignored, semantics are unchanged.
#define DMA_CHUNK(c, bufofs) do { \
    _Pragma("unroll") \
    for (int i = 0; i < 4; ++i) { \
        int row = i * 4 + dma_row; \
        int sx  = dma_s ^ (row & 7); \
        const float* src = state + (size_t)(rowbase + row) * SDIM + (c) * 64 + sx * 4; \
        __builtin_amdgcn_global_load_lds( \
            (const __attribute__((address_space(1))) void*)src, \
            (__attribute__((address_space(3))) void*)(region + (bufofs) + i * 1088), \
            16, 0, 2); \
    } } while (0)

#define WLOAD(c, wbuf) do { \
    _Pragma("unroll") \
    for (int n = 0; n < 4; ++n) { \
        _Pragma("unroll") \
        for (int ks = 0; ks < 2; ++ks) \
            wbuf[n * 2 + ks] = *(const bf16x8*)(W1T + (n * 16 + lr) * SDIM + (c) * 64 + ks * 32 + lq * 8); \
    } } while (0)

    const int rbase = (lr >> 2) * 1088 + (lr & 3) * 256;   // this lane's row base in a chunk buf
    const int xr    = lr & 7;

#define COMPUTE(bufofs, wbuf) do { \
    _Pragma("unroll") \
    for (int ks = 0; ks < 2; ++ks) { \
        f32x4 a0 = *(const f32x4*)(region + (bufofs) + rbase + (((ks * 8 + lq * 2 + 0) ^ xr) * 16)); \
        f32x4 a1 = *(const f32x4*)(region + (bufofs) + rbase + (((ks * 8 + lq * 2 + 1) ^ xr) * 16)); \
        bf16x8 a = cvt8(a0, a1); \
        _Pragma("unroll") \
        for (int n = 0; n < 4; ++n) \
            acc[n] = __builtin_amdgcn_mfma_f32_16x16x32_bf16(a, wbuf[n * 2 + ks], acc[n], 0, 0, 0); \
    } } while (0)

    f32x4 acc[4] = {zero4, zero4, zero4, zero4};
    bf16x8 w1fA[8], w1fB[8];

    // prologue: chunks 0 and 1 in flight (12 counted ops each: 4 DMA + 8 W)
    DMA_CHUNK(0, 0);
    WLOAD(0, w1fA);
    DMA_CHUNK(1, 4352);
    WLOAD(1, w1fB);

    #pragma unroll
    for (int k = 0; k < 8; ++k) {
        // wait: newest 12 outstanding = chunk k+1's DMA+W  =>  chunk k fully landed
        if (k == 7) asm volatile("s_waitcnt vmcnt(0)" ::: "memory");
        else        asm volatile("s_waitcnt vmcnt(12)" ::: "memory");
        __builtin_amdgcn_sched_barrier(0);
        if (k & 1) COMPUTE(4352, w1fB);
        else       COMPUTE(0,    w1fA);
        if (k < 6) {   // refill the buffer just consumed (ds_reads already drained)
            if (k & 1) { DMA_CHUNK(k + 2, 4352); WLOAD(k + 2, w1fB); }
            else       { DMA_CHUNK(k + 2, 0);    WLOAD(k + 2, w1fA); }
        }
    }
#undef DMA_CHUNK
#undef WLOAD
#undef COMPUTE

    // state buffers dead; overlay h1/h2 on buf0, mt on buf1
    __bf16* h1 = (__bf16*)region;             // [16][64] bf16 swz, 2 KB
    __bf16* h2 = (__bf16*)(region + 2048);    // [16][64] bf16 swz, 2 KB
    float*  mt = (float*)(region + 4352);     // [16][68] f32, 4352 B

    #pragma unroll
    for (int n = 0; n < 4; ++n) {
        #pragma unroll
        for (int r = 0; r < 4; ++r) {
            float v = acc[n][r] + bv1[n];
            v = (v >= 0.f) ? v : SLOPE * v;
            h1[swz(lq * 4 + r, n * 16 + lr)] = (__bf16)v;
        }
    }

    // ---------------- layer 2: [16 rows] x [32 cols], K=64 ----------------
    f32x4 c2[2] = {zero4, zero4};
    #pragma unroll
    for (int kk = 0; kk < 2; ++kk) {
        bf16x8 a = *(const bf16x8*)&h1[swz(lr, kk * 32 + lq * 8)];
        #pragma unroll
        for (int n = 0; n < 2; ++n) {
            bf16x8 b = *(const bf16x8*)(W2T + (n * 16 + lr) * 64 + kk * 32 + lq * 8);
            c2[n] = __builtin_amdgcn_mfma_f32_16x16x32_bf16(a, b, c2[n], 0, 0, 0);
        }
    }
    #pragma unroll
    for (int n = 0; n < 2; ++n) {
        #pragma unroll
        for (int r = 0; r < 4; ++r) {
            float v = c2[n][r] + bv2[n];
            v = (v >= 0.f) ? v : SLOPE * v;
            h2[swz(lq * 4 + r, n * 16 + lr)] = (__bf16)v;
        }
    }
    bf16x8 a3 = *(const bf16x8*)&h2[swz(lr, lq * 8)];   // into regs before mt use
    asm volatile("" ::: "memory");

    // ---------------- layer 3 + epilogue, 4 groups of 64 cols ----------------
    // Read-back column mapping: col = j*16 + q*4 -> each 4-lane row-group covers one
    // CONTIGUOUS 64-B line per nt store (no partial-line amplification, no L3 alloc).
    const int row = lane >> 2;            // 0..15 (read-back row)
    const int q   = lane & 3;             // 16-B sub-chunk within the 64-B line
    const size_t gbase = (size_t)(rowbase + row) * CDIM;
    float lp = 0.f;

    f32x4 nbuf[2][4];
    bf16x8 w3f[2][4];
    #pragma unroll
    for (int j = 0; j < 4; ++j) {
        nbuf[0][j] = __builtin_nontemporal_load((const f32x4*)(noise + gbase + j * 16 + q * 4));
        w3f[0][j]  = *(const bf16x8*)(W3T + (j * 16 + lr) * 32 + lq * 8);
    }

    #pragma unroll
    for (int g = 0; g < 4; ++g) {
        if (g < 3) {
            #pragma unroll
            for (int j = 0; j < 4; ++j) {
                nbuf[(g + 1) & 1][j] = __builtin_nontemporal_load(
                    (const f32x4*)(noise + gbase + (g + 1) * 64 + j * 16 + q * 4));
                w3f[(g + 1) & 1][j]  = *(const bf16x8*)(W3T + ((g + 1) * 64 + j * 16 + lr) * 32 + lq * 8);
            }
        }
        f32x4 b3v[4];
        #pragma unroll
        for (int j = 0; j < 4; ++j)
            b3v[j] = *(const f32x4*)(b3 + g * 64 + j * 16 + q * 4);

        // MFMA phase: 4 col-tiles -> LDS transpose buffer
        #pragma unroll
        for (int t = 0; t < 4; ++t) {
            f32x4 c = __builtin_amdgcn_mfma_f32_16x16x32_bf16(a3, w3f[g & 1][t], zero4, 0, 0, 0);
            #pragma unroll
            for (int r = 0; r < 4; ++r)
                mt[(lq * 4 + r) * MT_STRIDE + t * 16 + lr] = c[r];
        }
        // read-back phase: vectorized, contiguous per 4-lane group
        #pragma unroll
        for (int j = 0; j < 4; ++j) {
            f32x4 m4 = *(const f32x4*)&mt[row * MT_STRIDE + j * 16 + q * 4];
            f32x4 mean = m4 + b3v[j];
            f32x4 av = mean + nbuf[g & 1][j];
            __builtin_nontemporal_store(av, (f32x4*)(actions + gbase + g * 64 + j * 16 + q * 4));
            f32x4 zv = av - mean;          // replicate reference rounding exactly
            lp += -0.5f * (zv.x * zv.x + zv.y * zv.y + zv.z * zv.z + zv.w * zv.w) - 4.0f * HLP;
        }
    }
    // 4 lanes (q=0..3) share each row
    lp += __shfl_xor(lp, 1, 64);
    lp += __shfl_xor(lp, 2, 64);
    if (q == 0)
        logp[rowbase + row] = lp;
}

extern "C" void kernel_launch(void* const* d_in, const int* in_sizes, int n_in,
                              void* d_out, int out_size, void* d_ws, size_t ws_size,
                              hipStream_t stream)
{
    const float* state = (const float*)d_in[0];
    const float* W1    = (const float*)d_in[1];
    const float* b1    = (const float*)d_in[2];
    const float* W2    = (const float*)d_in[3];
    const float* b2    = (const float*)d_in[4];
    const float* W3    = (const float*)d_in[5];
    const float* b3    = (const float*)d_in[6];
    const float* noise = (const float*)d_in[7];

    if (ws_size < (size_t)WS_ELEMS * sizeof(__bf16)) return;  // need 86 KB scratch
    __bf16* ws = (__bf16*)d_ws;

    float* actions = (float*)d_out;
    float* logp    = actions + (size_t)BROWS * CDIM;

    prep_weights<<<(WS_ELEMS + 255) / 256, 256, 0, stream>>>(W1, W2, W3, ws);
    policy_fused<<<BROWS / 64, 256, 0, stream>>>(state, b1, b2, b3, noise, ws,
                                                 actions, logp);
}

// Round 13
// 60.063 us; speedup vs baseline: 1.2922x; 1.2922x over previous
//
#include <hip/hip_runtime.h>
#include <hip/hip_bf16.h>

typedef __attribute__((ext_vector_type(8))) __bf16 bf16x8;
typedef __attribute__((ext_vector_type(4))) float f32x4;

static constexpr int BROWS = 65536;
static constexpr int SDIM  = 512;
static constexpr int CDIM  = 256;
static constexpr float SLOPE = 0.01f;
static constexpr float HLP = 0.9189385332046727f;  // 0.5*log(2*pi)

// ws bf16 layout: W1T [64][512], W2T [32][64], W3T [256][32]
static constexpr int W1T_OFF = 0;
static constexpr int W2T_OFF = 64 * 512;
static constexpr int W3T_OFF = 64 * 512 + 32 * 64;
static constexpr int WS_ELEMS = W3T_OFF + 256 * 32;   // 43008

__global__ __launch_bounds__(256) void prep_weights(
    const float* __restrict__ W1, const float* __restrict__ W2,
    const float* __restrict__ W3, __bf16* __restrict__ ws)
{
    int tid = blockIdx.x * 256 + threadIdx.x;
    if (tid < 64 * 512) {                       // W1 [512][64] -> W1T [64][512]
        int n = tid >> 9, k = tid & 511;
        ws[W1T_OFF + tid] = (__bf16)W1[k * 64 + n];
    } else if (tid < 64 * 512 + 32 * 64) {      // W2 [64][32] -> W2T [32][64]
        int t = tid - 64 * 512;
        int n = t >> 6, k = t & 63;
        ws[W2T_OFF + t] = (__bf16)W2[k * 32 + n];
    } else if (tid < WS_ELEMS) {                // W3 [32][256] -> W3T [256][32]
        int t = tid - (64 * 512 + 32 * 64);
        int n = t >> 5, k = t & 31;
        ws[W3T_OFF + t] = (__bf16)W3[k * 256 + n];
    }
}

// swizzled LDS element index for bf16 [16][64] tiles: row stride 128 B
__device__ __forceinline__ int swz(int row, int elem) {
    return (row * 64 + elem) ^ ((row & 7) << 3);
}

__device__ __forceinline__ bf16x8 cvt8(f32x4 a, f32x4 b) {
    bf16x8 r = {(__bf16)a.x, (__bf16)a.y, (__bf16)a.z, (__bf16)a.w,
                (__bf16)b.x, (__bf16)b.y, (__bf16)b.z, (__bf16)b.w};
    return r;
}

static constexpr int MT_STRIDE = 68;     // floats
static constexpr int WREGION = 8704;     // per-wave: two 4352-B DMA chunk buffers

// R11 structure: counted-vmcnt global_load_lds streaming for state (cached reads),
// nt stores for actions, PLUS epilogue noise fully batch-issued (16 x f32x4, 64
// VGPR) behind a memory-clobber pin so all 16 lines are in flight at once and
// the read latency is paid once, not once per group.
__global__ __launch_bounds__(256, 4) void policy_fused(
    const float* __restrict__ state, const float* __restrict__ b1,
    const float* __restrict__ b2, const float* __restrict__ b3,
    const float* __restrict__ noise, const __bf16* __restrict__ ws,
    float* __restrict__ actions, float* __restrict__ logp)
{
    __shared__ __align__(64) char ldsraw[4 * WREGION];   // 34816 B

    const int tid  = threadIdx.x;
    const int wave = tid >> 6;
    const int lane = tid & 63;
    const int lr   = lane & 15;   // A-row / B-col index
    const int lq   = lane >> 4;   // k-chunk / C-row-quad index

    const int rowbase = blockIdx.x * 64 + wave * 16;   // this wave's 16 rows

    char* region = ldsraw + wave * WREGION;

    const __bf16* W1T = ws + W1T_OFF;
    const __bf16* W2T = ws + W2T_OFF;
    const __bf16* W3T = ws + W3T_OFF;

    const f32x4 zero4 = {0.f, 0.f, 0.f, 0.f};

    // preload tiny biases (reused across all waves -> cached, L1-hot)
    float bv1[4], bv2[2];
    #pragma unroll
    for (int n = 0; n < 4; ++n) bv1[n] = b1[n * 16 + lr];
    #pragma unroll
    for (int n = 0; n < 2; ++n) bv2[n] = b2[n * 16 + lr];

    // ---------------- layer 1: DMA-pipelined, 8 chunks of K=64 ----------------
    const int dma_row = lane >> 4;          // 0..3 within group
    const int dma_s   = lane & 15;          // 16-B slot

#define DMA_CHUNK(c, bufofs) do { \
    _Pragma("unroll") \
    for (int i = 0; i < 4; ++i) { \
        int row = i * 4 + dma_row; \
        int sx  = dma_s ^ (row & 7); \
        const float* src = state + (size_t)(rowbase + row) * SDIM + (c) * 64 + sx * 4; \
        __builtin_amdgcn_global_load_lds( \
            (const __attribute__((address_space(1))) void*)src, \
            (__attribute__((address_space(3))) void*)(region + (bufofs) + i * 1088), \
            16, 0, 0); \
    } } while (0)

#define WLOAD(c, wbuf) do { \
    _Pragma("unroll") \
    for (int n = 0; n < 4; ++n) { \
        _Pragma("unroll") \
        for (int ks = 0; ks < 2; ++ks) \
            wbuf[n * 2 + ks] = *(const bf16x8*)(W1T + (n * 16 + lr) * SDIM + (c) * 64 + ks * 32 + lq * 8); \
    } } while (0)

    const int rbase = (lr >> 2) * 1088 + (lr & 3) * 256;   // this lane's row base in a chunk buf
    const int xr    = lr & 7;

#define COMPUTE(bufofs, wbuf) do { \
    _Pragma("unroll") \
    for (int ks = 0; ks < 2; ++ks) { \
        f32x4 a0 = *(const f32x4*)(region + (bufofs) + rbase + (((ks * 8 + lq * 2 + 0) ^ xr) * 16)); \
        f32x4 a1 = *(const f32x4*)(region + (bufofs) + rbase + (((ks * 8 + lq * 2 + 1) ^ xr) * 16)); \
        bf16x8 a = cvt8(a0, a1); \
        _Pragma("unroll") \
        for (int n = 0; n < 4; ++n) \
            acc[n] = __builtin_amdgcn_mfma_f32_16x16x32_bf16(a, wbuf[n * 2 + ks], acc[n], 0, 0, 0); \
    } } while (0)

    f32x4 acc[4] = {zero4, zero4, zero4, zero4};
    bf16x8 w1fA[8], w1fB[8];

    // prologue: chunks 0 and 1 in flight (12 counted ops each: 4 DMA + 8 W)
    DMA_CHUNK(0, 0);
    WLOAD(0, w1fA);
    DMA_CHUNK(1, 4352);
    WLOAD(1, w1fB);

    #pragma unroll
    for (int k = 0; k < 8; ++k) {
        // wait: newest 12 outstanding = chunk k+1's DMA+W  =>  chunk k fully landed
        if (k == 7) asm volatile("s_waitcnt vmcnt(0)" ::: "memory");
        else        asm volatile("s_waitcnt vmcnt(12)" ::: "memory");
        __builtin_amdgcn_sched_barrier(0);
        if (k & 1) COMPUTE(4352, w1fB);
        else       COMPUTE(0,    w1fA);
        if (k < 6) {   // refill the buffer just consumed (ds_reads already drained)
            if (k & 1) { DMA_CHUNK(k + 2, 4352); WLOAD(k + 2, w1fB); }
            else       { DMA_CHUNK(k + 2, 0);    WLOAD(k + 2, w1fA); }
        }
    }
#undef DMA_CHUNK
#undef WLOAD
#undef COMPUTE

    // state buffers dead; overlay h1/h2 on buf0, mt on buf1
    __bf16* h1 = (__bf16*)region;             // [16][64] bf16 swz, 2 KB
    __bf16* h2 = (__bf16*)(region + 2048);    // [16][64] bf16 swz, 2 KB
    float*  mt = (float*)(region + 4352);     // [16][68] f32, 4352 B

    #pragma unroll
    for (int n = 0; n < 4; ++n) {
        #pragma unroll
        for (int r = 0; r < 4; ++r) {
            float v = acc[n][r] + bv1[n];
            v = (v >= 0.f) ? v : SLOPE * v;
            h1[swz(lq * 4 + r, n * 16 + lr)] = (__bf16)v;
        }
    }

    // ---------------- layer 2: [16 rows] x [32 cols], K=64 ----------------
    f32x4 c2[2] = {zero4, zero4};
    #pragma unroll
    for (int kk = 0; kk < 2; ++kk) {
        bf16x8 a = *(const bf16x8*)&h1[swz(lr, kk * 32 + lq * 8)];
        #pragma unroll
        for (int n = 0; n < 2; ++n) {
            bf16x8 b = *(const bf16x8*)(W2T + (n * 16 + lr) * 64 + kk * 32 + lq * 8);
            c2[n] = __builtin_amdgcn_mfma_f32_16x16x32_bf16(a, b, c2[n], 0, 0, 0);
        }
    }
    #pragma unroll
    for (int n = 0; n < 2; ++n) {
        #pragma unroll
        for (int r = 0; r < 4; ++r) {
            float v = c2[n][r] + bv2[n];
            v = (v >= 0.f) ? v : SLOPE * v;
            h2[swz(lq * 4 + r, n * 16 + lr)] = (__bf16)v;
        }
    }
    bf16x8 a3 = *(const bf16x8*)&h2[swz(lr, lq * 8)];   // into regs before mt use
    asm volatile("" ::: "memory");

    // ---------------- layer 3 + epilogue, 4 groups of 64 cols ----------------
    // Column mapping col = j*16 + q*4: each 4-lane row-group covers one CONTIGUOUS
    // 64-B line per nt store (no partial-line amplification, no L3 alloc for actions).
    const int row = lane >> 2;            // 0..15 (read-back row)
    const int q   = lane & 3;             // 16-B sub-chunk within the 64-B line
    const size_t gbase = (size_t)(rowbase + row) * CDIM;
    float lp = 0.f;

    // Batch-issue ALL noise loads for this wave's 16 rows x 256 cols slice owned by
    // this lane: 16 x f32x4 = 64 VGPR, all lines in flight simultaneously. The
    // memory-clobber asm pins them (loads cannot sink past it); first use waits once.
    f32x4 nv[16];
    #pragma unroll
    for (int g = 0; g < 4; ++g)
        #pragma unroll
        for (int j = 0; j < 4; ++j)
            nv[g * 4 + j] = *(const f32x4*)(noise + gbase + g * 64 + j * 16 + q * 4);
    asm volatile("" ::: "memory");

    bf16x8 w3f[2][4];
    #pragma unroll
    for (int j = 0; j < 4; ++j)
        w3f[0][j] = *(const bf16x8*)(W3T + (j * 16 + lr) * 32 + lq * 8);

    #pragma unroll
    for (int g = 0; g < 4; ++g) {
        if (g < 3) {
            #pragma unroll
            for (int j = 0; j < 4; ++j)
                w3f[(g + 1) & 1][j] = *(const bf16x8*)(W3T + ((g + 1) * 64 + j * 16 + lr) * 32 + lq * 8);
        }
        f32x4 b3v[4];
        #pragma unroll
        for (int j = 0; j < 4; ++j)
            b3v[j] = *(const f32x4*)(b3 + g * 64 + j * 16 + q * 4);

        // MFMA phase: 4 col-tiles -> LDS transpose buffer
        #pragma unroll
        for (int t = 0; t < 4; ++t) {
            f32x4 c = __builtin_amdgcn_mfma_f32_16x16x32_bf16(a3, w3f[g & 1][t], zero4, 0, 0, 0);
            #pragma unroll
            for (int r = 0; r < 4; ++r)
                mt[(lq * 4 + r) * MT_STRIDE + t * 16 + lr] = c[r];
        }
        // read-back phase: vectorized, contiguous per 4-lane group
        #pragma unroll
        for (int j = 0; j < 4; ++j) {
            f32x4 m4 = *(const f32x4*)&mt[row * MT_STRIDE + j * 16 + q * 4];
            f32x4 mean = m4 + b3v[j];
            f32x4 av = mean + nv[g * 4 + j];
            __builtin_nontemporal_store(av, (f32x4*)(actions + gbase + g * 64 + j * 16 + q * 4));
            f32x4 zv = av - mean;          // replicate reference rounding exactly
            lp += -0.5f * (zv.x * zv.x + zv.y * zv.y + zv.z * zv.z + zv.w * zv.w) - 4.0f * HLP;
        }
    }
    // 4 lanes (q=0..3) share each row
    lp += __shfl_xor(lp, 1, 64);
    lp += __shfl_xor(lp, 2, 64);
    if (q == 0)
        logp[rowbase + row] = lp;
}

extern "C" void kernel_launch(void* const* d_in, const int* in_sizes, int n_in,
                              void* d_out, int out_size, void* d_ws, size_t ws_size,
                              hipStream_t stream)
{
    const float* state = (const float*)d_in[0];
    const float* W1    = (const float*)d_in[1];
    const float* b1    = (const float*)d_in[2];
    const float* W2    = (const float*)d_in[3];
    const float* b2    = (const float*)d_in[4];
    const float* W3    = (const float*)d_in[5];
    const float* b3    = (const float*)d_in[6];
    const float* noise = (const float*)d_in[7];

    if (ws_size < (size_t)WS_ELEMS * sizeof(__bf16)) return;  // need 86 KB scratch
    __bf16* ws = (__bf16*)d_ws;

    float* actions = (float*)d_out;
    float* logp    = actions + (size_t)BROWS * CDIM;

    prep_weights<<<(WS_ELEMS + 255) / 256, 256, 0, stream>>>(W1, W2, W3, ws);
    policy_fused<<<BROWS / 64, 256, 0, stream>>>(state, b1, b2, b3, noise, ws,
                                                 actions, logp);
}

// Round 14
// 59.788 us; speedup vs baseline: 1.2981x; 1.0046x over previous
//
#include <hip/hip_runtime.h>
#include <hip/hip_bf16.h>

typedef __attribute__((ext_vector_type(8))) __bf16 bf16x8;
typedef __attribute__((ext_vector_type(4))) float f32x4;

static constexpr int BROWS = 65536;
static constexpr int SDIM  = 512;
static constexpr int CDIM  = 256;
static constexpr float SLOPE = 0.01f;
static constexpr float HLP = 0.9189385332046727f;  // 0.5*log(2*pi)

// ws bf16 layout: W1T [64][512], W2T [32][64], W3T [256][32]
static constexpr int W1T_OFF = 0;
static constexpr int W2T_OFF = 64 * 512;
static constexpr int W3T_OFF = 64 * 512 + 32 * 64;
static constexpr int WS_ELEMS = W3T_OFF + 256 * 32;   // 43008

__global__ __launch_bounds__(256) void prep_weights(
    const float* __restrict__ W1, const float* __restrict__ W2,
    const float* __restrict__ W3, __bf16* __restrict__ ws)
{
    int tid = blockIdx.x * 256 + threadIdx.x;
    if (tid < 64 * 512) {                       // W1 [512][64] -> W1T [64][512]
        int n = tid >> 9, k = tid & 511;
        ws[W1T_OFF + tid] = (__bf16)W1[k * 64 + n];
    } else if (tid < 64 * 512 + 32 * 64) {      // W2 [64][32] -> W2T [32][64]
        int t = tid - 64 * 512;
        int n = t >> 6, k = t & 63;
        ws[W2T_OFF + t] = (__bf16)W2[k * 32 + n];
    } else if (tid < WS_ELEMS) {                // W3 [32][256] -> W3T [256][32]
        int t = tid - (64 * 512 + 32 * 64);
        int n = t >> 5, k = t & 31;
        ws[W3T_OFF + t] = (__bf16)W3[k * 256 + n];
    }
}

// swizzled LDS element index for bf16 [16][64] tiles: row stride 128 B
__device__ __forceinline__ int swz(int row, int elem) {
    return (row * 64 + elem) ^ ((row & 7) << 3);
}

__device__ __forceinline__ bf16x8 cvt8(f32x4 a, f32x4 b) {
    bf16x8 r = {(__bf16)a.x, (__bf16)a.y, (__bf16)a.z, (__bf16)a.w,
                (__bf16)b.x, (__bf16)b.y, (__bf16)b.z, (__bf16)b.w};
    return r;
}

static constexpr int MT_STRIDE = 68;     // floats
static constexpr int WREGION = 8704;     // per-wave: two 4352-B DMA chunk buffers

// R11 base (counted-vmcnt DMA state streaming, nt action stores) + epilogue noise
// batch enforced via INLINE-ASM global_load_dwordx4: the compiler cannot split or
// re-schedule asm loads, so all 16 lines are genuinely in flight while layer-2/
// h2/a3 compute provides latency cover. W2 frags are pre-loaded and drained FIRST
// so no compiler vmcnt wait in layer 2 drains the noise batch early.
__global__ __launch_bounds__(256, 4) void policy_fused(
    const float* __restrict__ state, const float* __restrict__ b1,
    const float* __restrict__ b2, const float* __restrict__ b3,
    const float* __restrict__ noise, const __bf16* __restrict__ ws,
    float* __restrict__ actions, float* __restrict__ logp)
{
    __shared__ __align__(64) char ldsraw[4 * WREGION];   // 34816 B

    const int tid  = threadIdx.x;
    const int wave = tid >> 6;
    const int lane = tid & 63;
    const int lr   = lane & 15;   // A-row / B-col index
    const int lq   = lane >> 4;   // k-chunk / C-row-quad index

    const int rowbase = blockIdx.x * 64 + wave * 16;   // this wave's 16 rows

    char* region = ldsraw + wave * WREGION;

    const __bf16* W1T = ws + W1T_OFF;
    const __bf16* W2T = ws + W2T_OFF;
    const __bf16* W3T = ws + W3T_OFF;

    const f32x4 zero4 = {0.f, 0.f, 0.f, 0.f};

    // preload tiny biases (reused across all waves -> cached, L1-hot)
    float bv1[4], bv2[2];
    #pragma unroll
    for (int n = 0; n < 4; ++n) bv1[n] = b1[n * 16 + lr];
    #pragma unroll
    for (int n = 0; n < 2; ++n) bv2[n] = b2[n * 16 + lr];

    // ---------------- layer 1: DMA-pipelined, 8 chunks of K=64 ----------------
    const int dma_row = lane >> 4;          // 0..3 within group
    const int dma_s   = lane & 15;          // 16-B slot

#define DMA_CHUNK(c, bufofs) do { \
    _Pragma("unroll") \
    for (int i = 0; i < 4; ++i) { \
        int row = i * 4 + dma_row; \
        int sx  = dma_s ^ (row & 7); \
        const float* src = state + (size_t)(rowbase + row) * SDIM + (c) * 64 + sx * 4; \
        __builtin_amdgcn_global_load_lds( \
            (const __attribute__((address_space(1))) void*)src, \
            (__attribute__((address_space(3))) void*)(region + (bufofs) + i * 1088), \
            16, 0, 0); \
    } } while (0)

#define WLOAD(c, wbuf) do { \
    _Pragma("unroll") \
    for (int n = 0; n < 4; ++n) { \
        _Pragma("unroll") \
        for (int ks = 0; ks < 2; ++ks) \
            wbuf[n * 2 + ks] = *(const bf16x8*)(W1T + (n * 16 + lr) * SDIM + (c) * 64 + ks * 32 + lq * 8); \
    } } while (0)

    const int rbase = (lr >> 2) * 1088 + (lr & 3) * 256;   // this lane's row base in a chunk buf
    const int xr    = lr & 7;

#define COMPUTE(bufofs, wbuf) do { \
    _Pragma("unroll") \
    for (int ks = 0; ks < 2; ++ks) { \
        f32x4 a0 = *(const f32x4*)(region + (bufofs) + rbase + (((ks * 8 + lq * 2 + 0) ^ xr) * 16)); \
        f32x4 a1 = *(const f32x4*)(region + (bufofs) + rbase + (((ks * 8 + lq * 2 + 1) ^ xr) * 16)); \
        bf16x8 a = cvt8(a0, a1); \
        _Pragma("unroll") \
        for (int n = 0; n < 4; ++n) \
            acc[n] = __builtin_amdgcn_mfma_f32_16x16x32_bf16(a, wbuf[n * 2 + ks], acc[n], 0, 0, 0); \
    } } while (0)

    f32x4 acc[4] = {zero4, zero4, zero4, zero4};
    bf16x8 w1fA[8], w1fB[8];

    // prologue: chunks 0 and 1 in flight (12 counted ops each: 4 DMA + 8 W)
    DMA_CHUNK(0, 0);
    WLOAD(0, w1fA);
    DMA_CHUNK(1, 4352);
    WLOAD(1, w1fB);

    #pragma unroll
    for (int k = 0; k < 8; ++k) {
        // wait: newest 12 outstanding = chunk k+1's DMA+W  =>  chunk k fully landed
        if (k == 7) asm volatile("s_waitcnt vmcnt(0)" ::: "memory");
        else        asm volatile("s_waitcnt vmcnt(12)" ::: "memory");
        __builtin_amdgcn_sched_barrier(0);
        if (k & 1) COMPUTE(4352, w1fB);
        else       COMPUTE(0,    w1fA);
        if (k < 6) {   // refill the buffer just consumed (ds_reads already drained)
            if (k & 1) { DMA_CHUNK(k + 2, 4352); WLOAD(k + 2, w1fB); }
            else       { DMA_CHUNK(k + 2, 0);    WLOAD(k + 2, w1fA); }
        }
    }
#undef DMA_CHUNK
#undef WLOAD
#undef COMPUTE

    // state buffers dead; overlay h1/h2 on buf0, mt on buf1
    __bf16* h1 = (__bf16*)region;             // [16][64] bf16 swz, 2 KB
    __bf16* h2 = (__bf16*)(region + 2048);    // [16][64] bf16 swz, 2 KB
    float*  mt = (float*)(region + 4352);     // [16][68] f32, 4352 B

    #pragma unroll
    for (int n = 0; n < 4; ++n) {
        #pragma unroll
        for (int r = 0; r < 4; ++r) {
            float v = acc[n][r] + bv1[n];
            v = (v >= 0.f) ? v : SLOPE * v;
            h1[swz(lq * 4 + r, n * 16 + lr)] = (__bf16)v;
        }
    }

    // ---- preload W2 frags and DRAIN, so layer 2 has no VM dependency ----
    bf16x8 w2f[4];
    #pragma unroll
    for (int kk = 0; kk < 2; ++kk)
        #pragma unroll
        for (int n = 0; n < 2; ++n)
            w2f[kk * 2 + n] = *(const bf16x8*)(W2T + (n * 16 + lr) * 64 + kk * 32 + lq * 8);
    asm volatile("s_waitcnt vmcnt(0)" ::: "memory");
    __builtin_amdgcn_sched_barrier(0);

    // ---- FORCED noise batch: 16 inline-asm global_load_dwordx4 (64 VGPR) ----
    // Issued here so layer-2 + h2 + a3 (~500 cy of LDS/MFMA work) cover the latency.
    const int row = lane >> 2;            // 0..15 (epilogue read-back row)
    const int q   = lane & 3;             // 16-B sub-chunk within the 64-B line
    const size_t gbase = (size_t)(rowbase + row) * CDIM;
    const float* nbase = noise + gbase + q * 4;
    f32x4 nv[16];
#define NLOAD(i, BOFF) \
    asm volatile("global_load_dwordx4 %0, %1, off offset:" #BOFF \
                 : "=v"(nv[i]) : "v"(nbase))
    NLOAD(0, 0);     NLOAD(1, 64);    NLOAD(2, 128);   NLOAD(3, 192);
    NLOAD(4, 256);   NLOAD(5, 320);   NLOAD(6, 384);   NLOAD(7, 448);
    NLOAD(8, 512);   NLOAD(9, 576);   NLOAD(10, 640);  NLOAD(11, 704);
    NLOAD(12, 768);  NLOAD(13, 832);  NLOAD(14, 896);  NLOAD(15, 960);
#undef NLOAD

    // ---------------- layer 2: [16 rows] x [32 cols], K=64 (no VM waits) ----------------
    f32x4 c2[2] = {zero4, zero4};
    #pragma unroll
    for (int kk = 0; kk < 2; ++kk) {
        bf16x8 a = *(const bf16x8*)&h1[swz(lr, kk * 32 + lq * 8)];
        #pragma unroll
        for (int n = 0; n < 2; ++n)
            c2[n] = __builtin_amdgcn_mfma_f32_16x16x32_bf16(a, w2f[kk * 2 + n], c2[n], 0, 0, 0);
    }
    #pragma unroll
    for (int n = 0; n < 2; ++n) {
        #pragma unroll
        for (int r = 0; r < 4; ++r) {
            float v = c2[n][r] + bv2[n];
            v = (v >= 0.f) ? v : SLOPE * v;
            h2[swz(lq * 4 + r, n * 16 + lr)] = (__bf16)v;
        }
    }
    bf16x8 a3 = *(const bf16x8*)&h2[swz(lr, lq * 8)];   // into regs before mt use
    asm volatile("" ::: "memory");

    // ---------------- layer 3 + epilogue, 4 groups of 64 cols ----------------
    // Column mapping col = j*16 + q*4: each 4-lane row-group covers one CONTIGUOUS
    // 64-B line per nt store (no partial-line amplification, no L3 alloc for actions).
    float lp = 0.f;

    bf16x8 w3f[2][4];
    #pragma unroll
    for (int j = 0; j < 4; ++j)
        w3f[0][j] = *(const bf16x8*)(W3T + (j * 16 + lr) * 32 + lq * 8);

    // drain: all 16 noise asm loads (and w3f[0]) resident before first use.
    // sched_barrier stops the compiler hoisting nv uses above the wait (rule #18).
    asm volatile("s_waitcnt vmcnt(0)" ::: "memory");
    __builtin_amdgcn_sched_barrier(0);

    #pragma unroll
    for (int g = 0; g < 4; ++g) {
        if (g < 3) {
            #pragma unroll
            for (int j = 0; j < 4; ++j)
                w3f[(g + 1) & 1][j] = *(const bf16x8*)(W3T + ((g + 1) * 64 + j * 16 + lr) * 32 + lq * 8);
        }
        f32x4 b3v[4];
        #pragma unroll
        for (int j = 0; j < 4; ++j)
            b3v[j] = *(const f32x4*)(b3 + g * 64 + j * 16 + q * 4);

        // MFMA phase: 4 col-tiles -> LDS transpose buffer
        #pragma unroll
        for (int t = 0; t < 4; ++t) {
            f32x4 c = __builtin_amdgcn_mfma_f32_16x16x32_bf16(a3, w3f[g & 1][t], zero4, 0, 0, 0);
            #pragma unroll
            for (int r = 0; r < 4; ++r)
                mt[(lq * 4 + r) * MT_STRIDE + t * 16 + lr] = c[r];
        }
        // read-back phase: vectorized, contiguous per 4-lane group
        #pragma unroll
        for (int j = 0; j < 4; ++j) {
            f32x4 m4 = *(const f32x4*)&mt[row * MT_STRIDE + j * 16 + q * 4];
            f32x4 mean = m4 + b3v[j];
            f32x4 av = mean + nv[g * 4 + j];
            __builtin_nontemporal_store(av, (f32x4*)(actions + gbase + g * 64 + j * 16 + q * 4));
            f32x4 zv = av - mean;          // replicate reference rounding exactly
            lp += -0.5f * (zv.x * zv.x + zv.y * zv.y + zv.z * zv.z + zv.w * zv.w) - 4.0f * HLP;
        }
    }
    // 4 lanes (q=0..3) share each row
    lp += __shfl_xor(lp, 1, 64);
    lp += __shfl_xor(lp, 2, 64);
    if (q == 0)
        logp[rowbase + row] = lp;
}

extern "C" void kernel_launch(void* const* d_in, const int* in_sizes, int n_in,
                              void* d_out, int out_size, void* d_ws, size_t ws_size,
                              hipStream_t stream)
{
    const float* state = (const float*)d_in[0];
    const float* W1    = (const float*)d_in[1];
    const float* b1    = (const float*)d_in[2];
    const float* W2    = (const float*)d_in[3];
    const float* b2    = (const float*)d_in[4];
    const float* W3    = (const float*)d_in[5];
    const float* b3    = (const float*)d_in[6];
    const float* noise = (const float*)d_in[7];

    if (ws_size < (size_t)WS_ELEMS * sizeof(__bf16)) return;  // need 86 KB scratch
    __bf16* ws = (__bf16*)d_ws;

    float* actions = (float*)d_out;
    float* logp    = actions + (size_t)BROWS * CDIM;

    prep_weights<<<(WS_ELEMS + 255) / 256, 256, 0, stream>>>(W1, W2, W3, ws);
    policy_fused<<<BROWS / 64, 256, 0, stream>>>(state, b1, b2, b3, noise, ws,
                                                 actions, logp);
}